// Round 1
// baseline (118.570 us; speedup 1.0000x reference)
//
#include <hip/hip_runtime.h>

// Problem constants (match reference)
#define B_SZ   2
#define T_CTX  1024
#define E_IN   256
#define D_QK   64
#define DV_OUT 64
#define NROWS  (B_SZ * T_CTX)

// ---------------------------------------------------------------------------
// Kernel 1: per-row projections.
//   q = relu(x@Wq+bq); k = relu(x@Wk+bk); v = x@Wv+bv
//   qpb = q@W1[:64] + b1   (b1 folded in here)
//   kp  = k@W1[64:]
// One block (256 threads) per row; x-row staged in LDS.
// ---------------------------------------------------------------------------
__global__ __launch_bounds__(256) void proj_kernel(
    const float* __restrict__ x,
    const float* __restrict__ Wq, const float* __restrict__ bq,
    const float* __restrict__ Wk, const float* __restrict__ bk,
    const float* __restrict__ Wv, const float* __restrict__ bv,
    const float* __restrict__ W1, const float* __restrict__ b1,
    float* __restrict__ qpb, float* __restrict__ kp, float* __restrict__ v)
{
    __shared__ float xs[E_IN];
    __shared__ float qs[D_QK];
    __shared__ float ks[D_QK];

    const int row = blockIdx.x;
    const int t   = threadIdx.x;

    xs[t] = x[(size_t)row * E_IN + t];
    __syncthreads();

    const int d   = t & 63;
    const int grp = t >> 6;

    if (grp == 0) {
        float acc = bq[d];
        #pragma unroll 8
        for (int e = 0; e < E_IN; ++e) acc += xs[e] * Wq[e * D_QK + d];
        qs[d] = fmaxf(acc, 0.f);
    } else if (grp == 1) {
        float acc = bk[d];
        #pragma unroll 8
        for (int e = 0; e < E_IN; ++e) acc += xs[e] * Wk[e * D_QK + d];
        ks[d] = fmaxf(acc, 0.f);
    } else if (grp == 2) {
        float acc = bv[d];
        #pragma unroll 8
        for (int e = 0; e < E_IN; ++e) acc += xs[e] * Wv[e * DV_OUT + d];
        v[(size_t)row * DV_OUT + d] = acc;
    }
    __syncthreads();

    if (grp == 0) {
        float acc = b1[d];
        #pragma unroll 8
        for (int e = 0; e < D_QK; ++e) acc += qs[e] * W1[e * D_QK + d];
        qpb[(size_t)row * D_QK + d] = acc;
    } else if (grp == 1) {
        float acc = 0.f;
        #pragma unroll 8
        for (int e = 0; e < D_QK; ++e) acc += ks[e] * W1[(D_QK + e) * D_QK + d];
        kp[(size_t)row * D_QK + d] = acc;
    }
}

// ---------------------------------------------------------------------------
// Kernel 2: per-query-row scored attention.
//   s_j = b2 + sum_d relu(qpb[i,d] + kp[j,d]) * W2[d],  j <= i
//   softmax over j, then out = sum_j w_j * v[j,:]
// One block (256 threads = 4 waves) per (b,i).
// ---------------------------------------------------------------------------
__global__ __launch_bounds__(256) void attn_kernel(
    const float* __restrict__ qpb, const float* __restrict__ kp,
    const float* __restrict__ v,
    const float* __restrict__ W2, const float* __restrict__ b2,
    float* __restrict__ out)
{
    __shared__ float q4s[D_QK];
    __shared__ float w2s[D_QK];
    __shared__ float sc[T_CTX];
    __shared__ float red[8];
    __shared__ float part[4][DV_OUT];

    const int row  = blockIdx.x;
    const int b    = row >> 10;          // T_CTX = 1024
    const int i    = row & (T_CTX - 1);
    const int n    = i + 1;
    const int t    = threadIdx.x;
    const int lane = t & 63;
    const int wave = t >> 6;

    if (t < D_QK) { q4s[t] = qpb[(size_t)row * D_QK + t]; w2s[t] = W2[t]; }
    __syncthreads();

    const float bias2 = b2[0];
    const float4* q4 = (const float4*)q4s;
    const float4* w4 = (const float4*)w2s;

    float lmax = -INFINITY;
    for (int j = t; j < n; j += 256) {
        const float4* kr = (const float4*)(kp + ((size_t)(b * T_CTX + j)) * D_QK);
        float s = bias2;
        #pragma unroll
        for (int dd = 0; dd < D_QK / 4; ++dd) {
            float4 kv = kr[dd];
            float4 qv = q4[dd];
            float4 wv = w4[dd];
            s += fmaxf(qv.x + kv.x, 0.f) * wv.x;
            s += fmaxf(qv.y + kv.y, 0.f) * wv.y;
            s += fmaxf(qv.z + kv.z, 0.f) * wv.z;
            s += fmaxf(qv.w + kv.w, 0.f) * wv.w;
        }
        sc[j] = s;
        lmax = fmaxf(lmax, s);
    }

    // block max
    #pragma unroll
    for (int o = 32; o > 0; o >>= 1) lmax = fmaxf(lmax, __shfl_down(lmax, o, 64));
    if (lane == 0) red[wave] = lmax;
    __syncthreads();
    const float m = fmaxf(fmaxf(red[0], red[1]), fmaxf(red[2], red[3]));

    // exp + block sum
    float lsum = 0.f;
    for (int j = t; j < n; j += 256) {
        float p = __expf(sc[j] - m);
        sc[j] = p;
        lsum += p;
    }
    #pragma unroll
    for (int o = 32; o > 0; o >>= 1) lsum += __shfl_down(lsum, o, 64);
    if (lane == 0) red[4 + wave] = lsum;
    __syncthreads();
    const float denom = red[4] + red[5] + red[6] + red[7];

    // PV: lane = dv, wave = j-chunk (coalesced 256B v-row reads per wave)
    float acc = 0.f;
    for (int j = wave; j < n; j += 4) {
        acc += sc[j] * v[((size_t)(b * T_CTX + j)) * DV_OUT + lane];
    }
    part[wave][lane] = acc;
    __syncthreads();
    if (t < DV_OUT) {
        out[(size_t)row * DV_OUT + t] =
            (part[0][t] + part[1][t] + part[2][t] + part[3][t]) / denom;
    }
}

extern "C" void kernel_launch(void* const* d_in, const int* in_sizes, int n_in,
                              void* d_out, int out_size, void* d_ws, size_t ws_size,
                              hipStream_t stream) {
    const float* x  = (const float*)d_in[0];
    const float* Wq = (const float*)d_in[1];
    const float* bq = (const float*)d_in[2];
    const float* Wk = (const float*)d_in[3];
    const float* bk = (const float*)d_in[4];
    const float* Wv = (const float*)d_in[5];
    const float* bv = (const float*)d_in[6];
    const float* W1 = (const float*)d_in[7];
    const float* b1 = (const float*)d_in[8];
    const float* W2 = (const float*)d_in[9];
    const float* b2 = (const float*)d_in[10];
    float* out = (float*)d_out;

    float* ws  = (float*)d_ws;
    float* qpb = ws;                          // NROWS * D_QK
    float* kp  = ws + (size_t)NROWS * D_QK;   // NROWS * D_QK
    float* vv  = ws + (size_t)2 * NROWS * D_QK; // NROWS * DV_OUT

    proj_kernel<<<NROWS, 256, 0, stream>>>(x, Wq, bq, Wk, bk, Wv, bv, W1, b1,
                                           qpb, kp, vv);
    attn_kernel<<<NROWS, 256, 0, stream>>>(qpb, kp, vv, W2, b2, out);
}